// Round 4
// baseline (21323.755 us; speedup 1.0000x reference)
//
#include <hip/hip_runtime.h>
#include <stdint.h>

// ============================================================================
// LeapfrogIntegrator — round 4: correctness-first fp32 VALU kernel with
// runtime dtype detection (bf16 vs f32 inputs/outputs).
//
// Arrangement: one wave per 16-row tile; lane(q,c) (lane = 16q+c) owns row
// c's dims [16q, 16q+16). Cross-thread reductions (rank dot-products) via
// __shfl_xor over lanes {c,16+c,32+c,48+c}. All weights staged in LDS (f32).
//
// Numerics: np op-order fp32 v-updates (contract off, IEEE division),
// fp64 x-chain with exact mod-2pi wrap (== arctan2(sin,cos)), friction
// reuse (mu_half of step s == mu of step s+1, bit-identical).
// ============================================================================

#define HDT  0.05f
#define EPS  1e-8f
#define FRIC 0.05f

#define SU  68   // U row stride (words)
#define SWT 68   // Wf^T row stride
#define SWR 20   // W^T (dims x ranks) row stride

__device__ __forceinline__ float bf1(uint16_t v){ return __builtin_bit_cast(float,(uint32_t)v<<16); }
__device__ __forceinline__ uint16_t rb16(float f){            // RNE bf16 pack
  uint32_t u=__builtin_bit_cast(uint32_t,f);
  return (uint16_t)((u + 0x7fffu + ((u>>16)&1u))>>16);
}
__device__ __forceinline__ float ldw(const void* p,int i,bool isbf){
  return isbf ? bf1(((const uint16_t*)p)[i]) : ((const float*)p)[i];
}

__device__ __forceinline__ void ld16(const void* p, size_t base, bool isbf, float* out){
  if(isbf){
    const uint16_t* pp=(const uint16_t*)p+base;
    uint4 a=*(const uint4*)pp, b=*(const uint4*)(pp+8);
    uint32_t w[8]={a.x,a.y,a.z,a.w,b.x,b.y,b.z,b.w};
    #pragma unroll
    for(int k=0;k<8;++k){
      out[2*k  ]=__builtin_bit_cast(float,w[k]<<16);
      out[2*k+1]=__builtin_bit_cast(float,w[k]&0xffff0000u);
    }
  } else {
    const float* pp=(const float*)p+base;
    #pragma unroll
    for(int k=0;k<4;++k){
      float4 t=((const float4*)pp)[k];
      out[4*k]=t.x; out[4*k+1]=t.y; out[4*k+2]=t.z; out[4*k+3]=t.w;
    }
  }
}
__device__ __forceinline__ void st16(void* p, size_t base, bool isbf, const float* in){
  if(isbf){
    uint16_t* pp=(uint16_t*)p+base;
    uint32_t w[8];
    #pragma unroll
    for(int k=0;k<8;++k) w[k]=(uint32_t)rb16(in[2*k]) | ((uint32_t)rb16(in[2*k+1])<<16);
    *(uint4*)pp     = make_uint4(w[0],w[1],w[2],w[3]);
    *(uint4*)(pp+8) = make_uint4(w[4],w[5],w[6],w[7]);
  } else {
    float* pp=(float*)p+base;
    ((float4*)pp)[0]=make_float4(in[0],in[1],in[2],in[3]);
    ((float4*)pp)[1]=make_float4(in[4],in[5],in[6],in[7]);
    ((float4*)pp)[2]=make_float4(in[8],in[9],in[10],in[11]);
    ((float4*)pp)[3]=make_float4(in[12],in[13],in[14],in[15]);
  }
}

__global__ __launch_bounds__(256) void leapfrog(
    const void* __restrict__ xg, const void* __restrict__ vg,
    const void* __restrict__ fg, const void* __restrict__ Ug,
    const void* __restrict__ Wg, const void* __restrict__ Wfg,
    const void* __restrict__ bg, const int* __restrict__ stepsp,
    void* __restrict__ outp, int n_rows, int n_tiles)
{
  __shared__ float sU [16*SU];    // U[r][d]   at r*SU+d
  __shared__ float sWr[64*SWR];   // W^T[d][r] at d*SWR+r
  __shared__ float sWt[128*SWT];  // Wf^T[j][d] at j*SWT+d (j in [0,128))
  __shared__ float sb [64];

  const int tid=threadIdx.x, lane=tid&63, wid=tid>>6;
  const int q=lane>>4, c=lane&15;

  // ---- runtime dtype detection on U ----
  // bf16 data: even-indexed 16b halves are real values (~0.1*N) -> plausible.
  // f32 data read as bf16: even halves are mantissa bits -> random exponents.
  bool isbf;
  {
    const uint16_t* u=(const uint16_t*)Ug; int cnt=0;
    #pragma unroll
    for(int i=0;i<32;++i){ float t=fabsf(bf1(u[2*i])); cnt += ((t==0.f)||(t>1e-6f&&t<100.f)) ? 1:0; }
    isbf = (cnt>=24);
  }
  int steps = stepsp[0]; steps = steps<0 ? 0 : (steps>16 ? 16 : steps);

  // ---- stage weights as f32 in LDS ----
  for(int i=tid;i<1024;i+=256){ sU[(i>>6)*SU+(i&63)] = ldw(Ug,i,isbf); }
  for(int i=tid;i<1024;i+=256){ int r=i>>6,d=i&63; sWr[d*SWR+r] = ldw(Wg,i,isbf); }
  for(int i=tid;i<8192;i+=256){ int d=i>>7,j=i&127; sWt[j*SWT+d] = ldw(Wfg,i,isbf); }
  if(tid<64) sb[tid]=ldw(bg,tid,isbf);
  __syncthreads();

  const int tile = blockIdx.x*4 + wid;
  if(tile >= n_tiles) return;

  const size_t base=(size_t)(tile*16+c)*64 + 16*q;

  float vs[16],fs[16],mu[16],vh[16],gm[16],xin[16];
  double x64[16];
  ld16(xg,base,isbf,xin);
  ld16(vg,base,isbf,vs);
  ld16(fg,base,isbf,fs);
  #pragma unroll
  for(int i=0;i<16;++i) x64[i]=(double)xin[i];

  // gamma = ((v @ U^T)^2) @ W, for this thread's 16 dims
  auto christoffel=[&](const float* vv, float* g){
    float a2[16];
    #pragma unroll
    for(int r=0;r<16;++r){
      const float4* up=(const float4*)&sU[r*SU+16*q];
      float4 u0=up[0],u1=up[1],u2=up[2],u3=up[3];
      float t;
      t =       u0.x*vv[0];      t=fmaf(u0.y,vv[1],t);  t=fmaf(u0.z,vv[2],t);  t=fmaf(u0.w,vv[3],t);
      t=fmaf(u1.x,vv[4],t);  t=fmaf(u1.y,vv[5],t);  t=fmaf(u1.z,vv[6],t);  t=fmaf(u1.w,vv[7],t);
      t=fmaf(u2.x,vv[8],t);  t=fmaf(u2.y,vv[9],t);  t=fmaf(u2.z,vv[10],t); t=fmaf(u2.w,vv[11],t);
      t=fmaf(u3.x,vv[12],t); t=fmaf(u3.y,vv[13],t); t=fmaf(u3.z,vv[14],t); t=fmaf(u3.w,vv[15],t);
      t += __shfl_xor(t,16);
      t += __shfl_xor(t,32);
      a2[r]=t*t;
    }
    #pragma unroll
    for(int i=0;i<16;++i){
      const float4* wp=(const float4*)&sWr[(16*q+i)*SWR];
      float4 w0=wp[0],w1=wp[1],w2=wp[2],w3=wp[3];
      float t;
      t =       a2[0]*w0.x;      t=fmaf(a2[1],w0.y,t);  t=fmaf(a2[2],w0.z,t);  t=fmaf(a2[3],w0.w,t);
      t=fmaf(a2[4],w1.x,t);  t=fmaf(a2[5],w1.y,t);  t=fmaf(a2[6],w1.z,t);  t=fmaf(a2[7],w1.w,t);
      t=fmaf(a2[8],w2.x,t);  t=fmaf(a2[9],w2.y,t);  t=fmaf(a2[10],w2.z,t); t=fmaf(a2[11],w2.w,t);
      t=fmaf(a2[12],w3.x,t); t=fmaf(a2[13],w3.y,t); t=fmaf(a2[14],w3.z,t); t=fmaf(a2[15],w3.w,t);
      g[i]=t;
    }
  };

  // mu = FRIC*sigmoid([sin x, cos x] @ Wf^T + b), for this thread's 16 dims
  auto friction=[&](float* m){
    float sn[16],cn[16],gate[16];
    #pragma unroll
    for(int i=0;i<16;++i){ float xf=(float)x64[i]; sn[i]=__sinf(xf); cn[i]=__cosf(xf); }
    #pragma unroll
    for(int i=0;i<16;++i) gate[i]=sb[16*q+i];
    #pragma unroll
    for(int jj=0;jj<16;++jj){
      #pragma unroll
      for(int ow=0;ow<4;++ow){
        const int j=ow*16+jj;
        const int src=ow*16+c;               // lane owning dim j of row c
        float fsj=__shfl(sn[jj],src);
        float fcj=__shfl(cn[jj],src);
        const float4* w1=(const float4*)&sWt[j*SWT+16*q];
        const float4* w2=(const float4*)&sWt[(64+j)*SWT+16*q];
        #pragma unroll
        for(int ib=0;ib<4;++ib){
          float4 A=w1[ib], B=w2[ib];
          gate[4*ib+0]=fmaf(fcj,B.x,fmaf(fsj,A.x,gate[4*ib+0]));
          gate[4*ib+1]=fmaf(fcj,B.y,fmaf(fsj,A.y,gate[4*ib+1]));
          gate[4*ib+2]=fmaf(fcj,B.z,fmaf(fsj,A.z,gate[4*ib+2]));
          gate[4*ib+3]=fmaf(fcj,B.w,fmaf(fsj,A.w,gate[4*ib+3]));
        }
      }
    }
    #pragma unroll
    for(int i=0;i<16;++i){
      float sg=1.f/(1.f+__expf(-gate[i]));
      m[i]=FRIC*sg;
    }
  };

  friction(mu);                    // mu(x0); carried across half-steps

  for(int s=0;s<steps;++s){
    christoffel(vs,gm);
    {
      #pragma clang fp contract(off)
      #pragma unroll
      for(int i=0;i<16;++i){
        float t  = HDT*(fs[i]-gm[i]);            // np op order
        float num= vs[i]+t;
        float den= (1.f + HDT*mu[i]) + EPS;
        vh[i]= num/den;                          // IEEE division (no fast-math)
        float p  = 0.1f*vh[i];                   // matches np's f32 product
        double xx = x64[i] + (double)p;
        double n  = __builtin_rint(xx*0.15915494309189535);
        x64[i] = __builtin_fma(-6.283185307179586, n, xx);  // exact mod-2pi
      }
    }
    friction(mu);                  // mu_half == next step's mu (bit-identical)
    christoffel(vh,gm);
    {
      #pragma clang fp contract(off)
      #pragma unroll
      for(int i=0;i<16;++i){
        float t  = HDT*(fs[i]-gm[i]);
        float num= vh[i]+t;
        float den= (1.f + HDT*mu[i]) + EPS;
        vs[i]= num/den;
      }
    }
  }

  float xf[16];
  #pragma unroll
  for(int i=0;i<16;++i) xf[i]=(float)x64[i];

  // outputs: (x, v) concatenated; element offset n_rows*64 for v
  const size_t voff=(size_t)n_rows*64;
  if(isbf){
    uint16_t* o=(uint16_t*)outp;
    st16(o,        base, true, xf);
    st16(o+voff,   base, true, vs);
  } else {
    float* o=(float*)outp;
    st16(o,        base, false, xf);
    st16(o+voff,   base, false, vs);
  }
}

extern "C" void kernel_launch(void* const* d_in, const int* in_sizes, int n_in,
                              void* d_out, int out_size, void* d_ws, size_t ws_size,
                              hipStream_t stream) {
  const int n_rows  = in_sizes[0] / 64;
  const int n_tiles = n_rows / 16;
  const int grid    = (n_tiles + 3) / 4;       // 4 waves/block, 1 tile/wave
  leapfrog<<<dim3(grid), dim3(256), 0, stream>>>(
      d_in[0], d_in[1], d_in[2], d_in[3], d_in[4], d_in[5], d_in[6],
      (const int*)d_in[7], d_out, n_rows, n_tiles);
}